// Round 4
// baseline (6840.709 us; speedup 1.0000x reference)
//
#include <hip/hip_runtime.h>
#include <cmath>

// Leaky RNN:  h_t = 0.9 h_{t-1} + 0.1 tanh(h W_hh + u_t W_uh + b_h);  y_t = h_t W_hy + b_y
// B=64, T=2048, N_in=128, N_h=512, N_out=128.
//
// Phase 2 (critical path): one WG per batch row, 512 threads = 8 waves, waves_per_eu(2,2)
// -> 256-VGPR budget.  Wave w owns k-eighth [64w, 64w+64) (32 k-pairs = 8 h-quads).
// Lane l owns 8 columns c_i = 8l+i: i=0..2 STATIC in 24 named uint4 registers (96 VGPR),
// i=3..7 STREAMED from a packed f16 buffer (320 KB, L2-resident) through named
// double-buffered groups of 5 dwordx4.  Each h-quad ds_read_b128 broadcast feeds 32 dot2s.
// 8-way k-chunk reduction through LDS part2[8][512] (float4 writes, strided reads).
// 2 barriers/step.  NO arrays in the hot kernel (rule #20): everything named.
//
// ws: U (f16 [B*T][512], 128 MiB) | H (f16 [B*T][512], 128 MiB).
// Wpk (320 KiB) lives in d_out (dead until y_gemm overwrites it last).

#define NB 64
#define NT 2048
#define NI 128
#define NH 512
#define NO 128

typedef unsigned short u16;
typedef unsigned int u32;
typedef _Float16 half2_t __attribute__((ext_vector_type(2)));

__device__ __forceinline__ float fdot2(half2_t a, half2_t b, float c) {
#if __has_builtin(__builtin_amdgcn_fdot2)
    return __builtin_amdgcn_fdot2(a, b, c, false);
#else
    return c + (float)a[0] * (float)b[0] + (float)a[1] * (float)b[1];
#endif
}
#define BCH(u) __builtin_bit_cast(half2_t, (u))

__device__ __forceinline__ u16 ftoh(float x) { return __builtin_bit_cast(u16, (_Float16)x); }
__device__ __forceinline__ float htof(u16 x) { return (float)__builtin_bit_cast(_Float16, x); }

__device__ __forceinline__ u32 ldpair(const float* __restrict__ W, int k, int c) {
    half2_t v;
    v[0] = (_Float16)W[(size_t)k * NH + c];
    v[1] = (_Float16)W[(size_t)(k + 1) * NH + c];
    return __builtin_bit_cast(u32, v);
}

// ---------------- Phase 0: pack streamed W_hh slice (f16, exact consumer order) ----------
// Consumer thread (w,l), group q (0..7), slot i3 (0..4): Wpk[w*2560 + (q*5+i3)*64 + l]
// = quad for col 8l+(i3+3), k-pairs 32w+4q+{0..3} (k = 64w+8q+2j).
__global__ __launch_bounds__(256) void wpack(const float* __restrict__ Whh,
                                             uint4* __restrict__ Wpk) {
    const int idx = blockIdx.x * 256 + threadIdx.x;   // 0..20479
    const int l = idx & 63;
    const int i3 = (idx >> 6) % 5;
    const int q = (idx / 320) & 7;
    const int w = idx / 2560;
    const int c = 8 * l + i3 + 3;
    const int kb = 64 * w + 8 * q;
    uint4 o;
    o.x = ldpair(Whh, kb + 0, c);
    o.y = ldpair(Whh, kb + 2, c);
    o.z = ldpair(Whh, kb + 4, c);
    o.w = ldpair(Whh, kb + 6, c);
    Wpk[idx] = o;
}

// ---------------- Phase 1: U[m][n] = u[m][:] @ W_uh[:,n] + b_h[n]  (f16 out) ----------------
__global__ __launch_bounds__(256) void u_gemm(
        const float* __restrict__ A,    // u  [M][NI]
        const float* __restrict__ Bw,   // W_uh [NI][NH]
        const float* __restrict__ bh,   // [NH]
        u16* __restrict__ C) {          // U [M][NH] f16
    const int n0 = blockIdx.x * 64;
    const int m0 = blockIdx.y * 64;
    const int tid = threadIdx.x;
    const int tn = tid & 15, tm = tid >> 4;
    __shared__ float As[64][68];   // [k][m]
    __shared__ float Bs[64][68];   // [k][n]
    float acc[4][4] = {};
    for (int k0 = 0; k0 < NI; k0 += 64) {
        const int r = tid >> 4, c4 = tid & 15;
        #pragma unroll
        for (int p = 0; p < 4; ++p) {
            const int row = r + p * 16;
            float4 v = *reinterpret_cast<const float4*>(&A[(size_t)(m0 + row) * NI + k0 + c4 * 4]);
            As[c4 * 4 + 0][row] = v.x; As[c4 * 4 + 1][row] = v.y;
            As[c4 * 4 + 2][row] = v.z; As[c4 * 4 + 3][row] = v.w;
        }
        #pragma unroll
        for (int p = 0; p < 4; ++p) {
            const int row = r + p * 16;
            float4 v = *reinterpret_cast<const float4*>(&Bw[(size_t)(k0 + row) * NH + n0 + c4 * 4]);
            *reinterpret_cast<float4*>(&Bs[row][c4 * 4]) = v;
        }
        __syncthreads();
        #pragma unroll
        for (int kk = 0; kk < 64; ++kk) {
            float4 av = *reinterpret_cast<const float4*>(&As[kk][tm * 4]);
            float4 bv = *reinterpret_cast<const float4*>(&Bs[kk][tn * 4]);
            const float am[4] = {av.x, av.y, av.z, av.w};
            const float bn[4] = {bv.x, bv.y, bv.z, bv.w};
            #pragma unroll
            for (int i = 0; i < 4; ++i)
                #pragma unroll
                for (int j = 0; j < 4; ++j)
                    acc[i][j] += am[i] * bn[j];
        }
        __syncthreads();
    }
    float bias[4];
    #pragma unroll
    for (int j = 0; j < 4; ++j) bias[j] = bh[n0 + tn * 4 + j];
    #pragma unroll
    for (int i = 0; i < 4; ++i) {
        const int m = m0 + tm * 4 + i;
        ushort4 out;
        out.x = ftoh(acc[i][0] + bias[0]);
        out.y = ftoh(acc[i][1] + bias[1]);
        out.z = ftoh(acc[i][2] + bias[2]);
        out.w = ftoh(acc[i][3] + bias[3]);
        *reinterpret_cast<ushort4*>(&C[(size_t)m * NH + n0 + tn * 4]) = out;
    }
}

// ---------------- Phase 2: sequential recurrence ----------------
#define DOTQ(HQ, WQ, ACC)                          \
    ACC = fdot2(BCH((HQ).x), BCH((WQ).x), ACC);    \
    ACC = fdot2(BCH((HQ).y), BCH((WQ).y), ACC);    \
    ACC = fdot2(BCH((HQ).z), BCH((WQ).z), ACC);    \
    ACC = fdot2(BCH((HQ).w), BCH((WQ).w), ACC);

// One group: h-quad broadcast, 8 column-dots (3 static + 5 streamed), then refill the
// consumed buffer with group PG's quads (stream repeats every step, so PG wraps mod 8).
#define GROUP(Q, SA, SB, SC, B0, B1, B2, B3, B4, PG) {           \
    const uint4 hq = hqb[Q];                                     \
    DOTQ(hq, SA, acc0) DOTQ(hq, SB, acc1) DOTQ(hq, SC, acc2)     \
    DOTQ(hq, B0, acc3) DOTQ(hq, B1, acc4) DOTQ(hq, B2, acc5)     \
    DOTQ(hq, B3, acc6) DOTQ(hq, B4, acc7)                        \
    B0 = wqb[((PG) * 5 + 0) * 64];                               \
    B1 = wqb[((PG) * 5 + 1) * 64];                               \
    B2 = wqb[((PG) * 5 + 2) * 64];                               \
    B3 = wqb[((PG) * 5 + 3) * 64];                               \
    B4 = wqb[((PG) * 5 + 4) * 64]; }

#define SINIT(I, Q, VAR) {                         \
    const int c_ = 8 * l + (I);                    \
    const int kb_ = 64 * w + 8 * (Q);              \
    VAR.x = ldpair(Whh, kb_ + 0, c_);              \
    VAR.y = ldpair(Whh, kb_ + 2, c_);              \
    VAR.z = ldpair(Whh, kb_ + 4, c_);              \
    VAR.w = ldpair(Whh, kb_ + 6, c_); }

__global__ __attribute__((amdgpu_flat_work_group_size(512, 512), amdgpu_waves_per_eu(2, 2)))
void rnn_seq(const float* __restrict__ Whh,   // [NH][NH] fp32 (one-time static load)
             const float* __restrict__ h0,    // [NB][NH]
             const u16* __restrict__ U,       // [NB*NT][NH] f16
             u16* __restrict__ H,             // [NB*NT][NH] f16 (out)
             const uint4* __restrict__ Wpk) { // packed streamed slice, 20480 uint4
    const int b = blockIdx.x;
    const int tid = threadIdx.x;
    const int w = tid >> 6, l = tid & 63;

    __shared__ __align__(16) u32 h2u[NH / 2];       // h as f16 pairs, 1 KiB
    __shared__ __align__(16) float part2[8][NH];    // k-chunk partials, 16 KiB

    // 24 named static quads: cols 8l+{0,1,2} x 8 quads over k in [64w, 64w+64).
    uint4 s0_0, s0_1, s0_2, s0_3, s0_4, s0_5, s0_6, s0_7;
    uint4 s1_0, s1_1, s1_2, s1_3, s1_4, s1_5, s1_6, s1_7;
    uint4 s2_0, s2_1, s2_2, s2_3, s2_4, s2_5, s2_6, s2_7;
    SINIT(0, 0, s0_0) SINIT(0, 1, s0_1) SINIT(0, 2, s0_2) SINIT(0, 3, s0_3)
    SINIT(0, 4, s0_4) SINIT(0, 5, s0_5) SINIT(0, 6, s0_6) SINIT(0, 7, s0_7)
    SINIT(1, 0, s1_0) SINIT(1, 1, s1_1) SINIT(1, 2, s1_2) SINIT(1, 3, s1_3)
    SINIT(1, 4, s1_4) SINIT(1, 5, s1_5) SINIT(1, 6, s1_6) SINIT(1, 7, s1_7)
    SINIT(2, 0, s2_0) SINIT(2, 1, s2_1) SINIT(2, 2, s2_2) SINIT(2, 3, s2_3)
    SINIT(2, 4, s2_4) SINIT(2, 5, s2_5) SINIT(2, 6, s2_6) SINIT(2, 7, s2_7)

    float hreg = h0[b * NH + tid];
    if (tid < NH / 2) {
        float2 hv = *reinterpret_cast<const float2*>(&h0[b * NH + 2 * tid]);
        half2_t hp; hp[0] = (_Float16)hv.x; hp[1] = (_Float16)hv.y;
        h2u[tid] = __builtin_bit_cast(u32, hp);
    }
    __syncthreads();

    const u16* __restrict__ Urow = U + (size_t)b * NT * NH;
    u16* __restrict__ Hrow = H + (size_t)b * NT * NH;
    const uint4* __restrict__ wqb = Wpk + (size_t)w * 2560 + l;        // + (q*5+i3)*64
    const uint4* __restrict__ hqb = reinterpret_cast<const uint4*>(h2u) + (w << 3);

    // Stream double-buffer: named groups of 5 (rule #20: no arrays).
    uint4 pa0, pa1, pa2, pa3, pa4, pb0, pb1, pb2, pb3, pb4;
    pa0 = wqb[0 * 64]; pa1 = wqb[1 * 64]; pa2 = wqb[2 * 64]; pa3 = wqb[3 * 64]; pa4 = wqb[4 * 64];
    pb0 = wqb[5 * 64]; pb1 = wqb[6 * 64]; pb2 = wqb[7 * 64]; pb3 = wqb[8 * 64]; pb4 = wqb[9 * 64];

    for (int t = 0; t < NT; ++t) {
        const u16 ubits = Urow[(size_t)t * NH + tid];   // consumed in update phase

        float acc0 = 0.f, acc1 = 0.f, acc2 = 0.f, acc3 = 0.f;
        float acc4 = 0.f, acc5 = 0.f, acc6 = 0.f, acc7 = 0.f;

        GROUP(0, s0_0, s1_0, s2_0, pa0, pa1, pa2, pa3, pa4, 2)
        GROUP(1, s0_1, s1_1, s2_1, pb0, pb1, pb2, pb3, pb4, 3)
        GROUP(2, s0_2, s1_2, s2_2, pa0, pa1, pa2, pa3, pa4, 4)
        GROUP(3, s0_3, s1_3, s2_3, pb0, pb1, pb2, pb3, pb4, 5)
        GROUP(4, s0_4, s1_4, s2_4, pa0, pa1, pa2, pa3, pa4, 6)
        GROUP(5, s0_5, s1_5, s2_5, pb0, pb1, pb2, pb3, pb4, 7)
        GROUP(6, s0_6, s1_6, s2_6, pa0, pa1, pa2, pa3, pa4, 0)   // wraps: next step's g0
        GROUP(7, s0_7, s1_7, s2_7, pb0, pb1, pb2, pb3, pb4, 1)   // wraps: next step's g1

        // Partials: cols 8l+i are contiguous -> two float4 LDS writes.
        float4 w0; w0.x = acc0; w0.y = acc1; w0.z = acc2; w0.w = acc3;
        float4 w1; w1.x = acc4; w1.y = acc5; w1.z = acc6; w1.w = acc7;
        *reinterpret_cast<float4*>(&part2[w][8 * l]) = w0;
        *reinterpret_cast<float4*>(&part2[w][8 * l + 4]) = w1;
        __syncthreads();

        // Update h[tid]: 8-way k-chunk reduction (strided, conflict-free), + U, tanh, leak.
        const float pre = ((part2[0][tid] + part2[1][tid]) + (part2[2][tid] + part2[3][tid]))
                        + ((part2[4][tid] + part2[5][tid]) + (part2[6][tid] + part2[7][tid]))
                        + htof(ubits);
        const float e = __expf(2.f * pre);
        hreg = 0.9f * hreg + 0.1f * (1.f - 2.f / (e + 1.f));
        const u16 hb = ftoh(hreg);
        Hrow[(size_t)t * NH + tid] = hb;
        reinterpret_cast<u16*>(h2u)[tid] = hb;
        __syncthreads();
    }
}

// ---------------- Phase 3: Y[m][n] = H[m][:] @ W_hy[:,n] + b_y[n]  (fp32 out) ----------------
__global__ __launch_bounds__(256) void y_gemm(
        const u16* __restrict__ H,      // [M][NH] f16
        const float* __restrict__ Why,  // [NH][NO]
        const float* __restrict__ by,   // [NO]
        float* __restrict__ Y) {        // [M][NO]
    const int m0 = blockIdx.x * 64;
    const int tid = threadIdx.x;
    const int tn = tid & 15, tm = tid >> 4;
    __shared__ float As[64][68];    // [k][m]
    __shared__ float Bs[64][132];   // [k][n]
    float acc[4][8] = {};
    for (int k0 = 0; k0 < NH; k0 += 64) {
        #pragma unroll
        for (int p = 0; p < 4; ++p) {
            const int idx = tid + p * 256;
            const int r = idx >> 4;
            const int c4 = idx & 15;
            ushort4 v = *reinterpret_cast<const ushort4*>(&H[(size_t)(m0 + r) * NH + k0 + c4 * 4]);
            As[c4 * 4 + 0][r] = htof(v.x); As[c4 * 4 + 1][r] = htof(v.y);
            As[c4 * 4 + 2][r] = htof(v.z); As[c4 * 4 + 3][r] = htof(v.w);
        }
        #pragma unroll
        for (int p = 0; p < 8; ++p) {
            const int idx = tid + p * 256;
            const int r = idx >> 5;
            const int c4 = idx & 31;
            float4 v = *reinterpret_cast<const float4*>(&Why[(size_t)(k0 + r) * NO + c4 * 4]);
            *reinterpret_cast<float4*>(&Bs[r][c4 * 4]) = v;
        }
        __syncthreads();
        #pragma unroll
        for (int kk = 0; kk < 64; ++kk) {
            float4 av = *reinterpret_cast<const float4*>(&As[kk][tm * 4]);
            float4 b0 = *reinterpret_cast<const float4*>(&Bs[kk][tn * 8]);
            float4 b1 = *reinterpret_cast<const float4*>(&Bs[kk][tn * 8 + 4]);
            const float am[4] = {av.x, av.y, av.z, av.w};
            const float bn[8] = {b0.x, b0.y, b0.z, b0.w, b1.x, b1.y, b1.z, b1.w};
            #pragma unroll
            for (int i = 0; i < 4; ++i)
                #pragma unroll
                for (int j = 0; j < 8; ++j)
                    acc[i][j] += am[i] * bn[j];
        }
        __syncthreads();
    }
    float bias[8];
    #pragma unroll
    for (int j = 0; j < 8; ++j) bias[j] = by[tn * 8 + j];
    #pragma unroll
    for (int i = 0; i < 4; ++i) {
        const int m = m0 + tm * 4 + i;
        float4 o0, o1;
        o0.x = acc[i][0] + bias[0]; o0.y = acc[i][1] + bias[1];
        o0.z = acc[i][2] + bias[2]; o0.w = acc[i][3] + bias[3];
        o1.x = acc[i][4] + bias[4]; o1.y = acc[i][5] + bias[5];
        o1.z = acc[i][6] + bias[6]; o1.w = acc[i][7] + bias[7];
        *reinterpret_cast<float4*>(&Y[(size_t)m * NO + tn * 8]) = o0;
        *reinterpret_cast<float4*>(&Y[(size_t)m * NO + tn * 8 + 4]) = o1;
    }
}

extern "C" void kernel_launch(void* const* d_in, const int* in_sizes, int n_in,
                              void* d_out, int out_size, void* d_ws, size_t ws_size,
                              hipStream_t stream) {
    const float* u   = (const float*)d_in[0];   // [64][2048][128]
    const float* h0  = (const float*)d_in[1];   // [64][512]
    const float* Wuh = (const float*)d_in[2];   // [128][512]
    const float* Whh = (const float*)d_in[3];   // [512][512]
    const float* Why = (const float*)d_in[4];   // [512][128]
    const float* bh  = (const float*)d_in[5];   // [512]
    const float* by  = (const float*)d_in[6];   // [128]
    float* y = (float*)d_out;                   // [64][2048][128] fp32

    u16* Uws = (u16*)d_ws;                       // 128 MiB
    u16* Hws = Uws + (size_t)NB * NT * NH;       // 128 MiB
    uint4* Wpk = (uint4*)d_out;                  // 320 KiB, dead until y_gemm
    (void)in_sizes; (void)n_in; (void)out_size; (void)ws_size;

    wpack<<<dim3(80), 256, 0, stream>>>(Whh, Wpk);
    u_gemm<<<dim3(NH / 64, (NB * NT) / 64), 256, 0, stream>>>(u, Wuh, bh, Uws);
    rnn_seq<<<dim3(NB), 512, 0, stream>>>(Whh, h0, Uws, Hws, Wpk);
    y_gemm<<<dim3((NB * NT) / 64), 256, 0, stream>>>(Hws, Why, by, y);
}

// Round 5
// 6325.711 us; speedup vs baseline: 1.0814x; 1.0814x over previous
//
#include <hip/hip_runtime.h>
#include <cmath>

// Leaky RNN:  h_t = 0.9 h_{t-1} + 0.1 tanh(h W_hh + u_t W_uh + b_h);  y_t = h_t W_hy + b_y
// B=64, T=2048, N_in=128, N_h=512, N_out=128.
//
// Phase 2 (critical path): one WG per batch row, 512 threads = 8 waves,
// __launch_bounds__(512) ONLY (no occupancy hint -> allocator may use up to 256 VGPR,
// the residency cap for 8-wave WGs).  Wave w owns k-eighth [64w,64w+64) = 8 h-quads.
// Lane l owns 8 cols 8l+i: i=0..4 STATIC in 40 named uint4 (160 VGPR), i=5..7 STREAMED
// (24 quads/step = 192 KiB/step/CU from L2, under the VALU floor) via named double
// buffers.  All W pre-packed to f16 in exact consumption order (Wpk, 512 KiB, in d_out).
// Each h-quad ds_read_b128 broadcast feeds 32 dot2s.  Partials via padded LDS, 2
// barriers/step.  NO arrays in the hot kernel (rule #20).
//
// ws: U (f16 [B*T][512], 128 MiB) | H (f16 [B*T][512], 128 MiB).

#define NB 64
#define NT 2048
#define NI 128
#define NH 512
#define NO 128

typedef unsigned short u16;
typedef unsigned int u32;
typedef _Float16 half2_t __attribute__((ext_vector_type(2)));

__device__ __forceinline__ float fdot2(half2_t a, half2_t b, float c) {
#if __has_builtin(__builtin_amdgcn_fdot2)
    return __builtin_amdgcn_fdot2(a, b, c, false);
#else
    return c + (float)a[0] * (float)b[0] + (float)a[1] * (float)b[1];
#endif
}
#define BCH(u) __builtin_bit_cast(half2_t, (u))

__device__ __forceinline__ u16 ftoh(float x) { return __builtin_bit_cast(u16, (_Float16)x); }
__device__ __forceinline__ float htof(u16 x) { return (float)__builtin_bit_cast(_Float16, x); }

__device__ __forceinline__ u32 ldpair(const float* __restrict__ W, int k, int c) {
    half2_t v;
    v[0] = (_Float16)W[(size_t)k * NH + c];
    v[1] = (_Float16)W[(size_t)(k + 1) * NH + c];
    return __builtin_bit_cast(u32, v);
}

// ---------------- Phase 0: pack ALL of W_hh to f16 in consumption order ----------------
// sec0 (static, idx<20480): w=idx/2560, t2=(idx%2560)>>6 (q=t2/5,i=t2%5), l=idx&63,
//   col=8l+i.   sec1 (streamed): j=idx-20480, w=j/1536, t2=(j%1536)>>6 (q=t2/3,i=t2%3),
//   l=j&63, col=8l+5+i.  Quad = k-pairs kb+{0,2,4,6}, kb=64w+8q.
__global__ __launch_bounds__(256) void wpack(const float* __restrict__ Whh,
                                             uint4* __restrict__ Wpk) {
    const int idx = blockIdx.x * 256 + threadIdx.x;   // 0..32767
    int w, q, i, l, col;
    if (idx < 20480) {
        w = idx / 2560;
        const int r = idx - w * 2560;
        const int t2 = r >> 6;
        q = t2 / 5; i = t2 - 5 * q; l = r & 63;
        col = 8 * l + i;
    } else {
        const int j = idx - 20480;
        w = j / 1536;
        const int r = j - w * 1536;
        const int t2 = r >> 6;
        q = t2 / 3; i = t2 - 3 * q; l = r & 63;
        col = 8 * l + 5 + i;
    }
    const int kb = 64 * w + 8 * q;
    uint4 o;
    o.x = ldpair(Whh, kb + 0, col);
    o.y = ldpair(Whh, kb + 2, col);
    o.z = ldpair(Whh, kb + 4, col);
    o.w = ldpair(Whh, kb + 6, col);
    Wpk[idx] = o;
}

// ---------------- Phase 1: U[m][n] = u[m][:] @ W_uh[:,n] + b_h[n]  (f16 out) ----------------
__global__ __launch_bounds__(256) void u_gemm(
        const float* __restrict__ A,    // u  [M][NI]
        const float* __restrict__ Bw,   // W_uh [NI][NH]
        const float* __restrict__ bh,   // [NH]
        u16* __restrict__ C) {          // U [M][NH] f16
    const int n0 = blockIdx.x * 64;
    const int m0 = blockIdx.y * 64;
    const int tid = threadIdx.x;
    const int tn = tid & 15, tm = tid >> 4;
    __shared__ float As[64][68];   // [k][m]
    __shared__ float Bs[64][68];   // [k][n]
    float acc[4][4] = {};
    for (int k0 = 0; k0 < NI; k0 += 64) {
        const int r = tid >> 4, c4 = tid & 15;
        #pragma unroll
        for (int p = 0; p < 4; ++p) {
            const int row = r + p * 16;
            float4 v = *reinterpret_cast<const float4*>(&A[(size_t)(m0 + row) * NI + k0 + c4 * 4]);
            As[c4 * 4 + 0][row] = v.x; As[c4 * 4 + 1][row] = v.y;
            As[c4 * 4 + 2][row] = v.z; As[c4 * 4 + 3][row] = v.w;
        }
        #pragma unroll
        for (int p = 0; p < 4; ++p) {
            const int row = r + p * 16;
            float4 v = *reinterpret_cast<const float4*>(&Bw[(size_t)(k0 + row) * NH + n0 + c4 * 4]);
            *reinterpret_cast<float4*>(&Bs[row][c4 * 4]) = v;
        }
        __syncthreads();
        #pragma unroll
        for (int kk = 0; kk < 64; ++kk) {
            float4 av = *reinterpret_cast<const float4*>(&As[kk][tm * 4]);
            float4 bv = *reinterpret_cast<const float4*>(&Bs[kk][tn * 4]);
            const float am[4] = {av.x, av.y, av.z, av.w};
            const float bn[4] = {bv.x, bv.y, bv.z, bv.w};
            #pragma unroll
            for (int i = 0; i < 4; ++i)
                #pragma unroll
                for (int j = 0; j < 4; ++j)
                    acc[i][j] += am[i] * bn[j];
        }
        __syncthreads();
    }
    float bias[4];
    #pragma unroll
    for (int j = 0; j < 4; ++j) bias[j] = bh[n0 + tn * 4 + j];
    #pragma unroll
    for (int i = 0; i < 4; ++i) {
        const int m = m0 + tm * 4 + i;
        ushort4 out;
        out.x = ftoh(acc[i][0] + bias[0]);
        out.y = ftoh(acc[i][1] + bias[1]);
        out.z = ftoh(acc[i][2] + bias[2]);
        out.w = ftoh(acc[i][3] + bias[3]);
        *reinterpret_cast<ushort4*>(&C[(size_t)m * NH + n0 + tn * 4]) = out;
    }
}

// ---------------- Phase 2: sequential recurrence ----------------
#define DOTQ(HQ, WQ, ACC)                          \
    ACC = fdot2(BCH((HQ).x), BCH((WQ).x), ACC);    \
    ACC = fdot2(BCH((HQ).y), BCH((WQ).y), ACC);    \
    ACC = fdot2(BCH((HQ).z), BCH((WQ).z), ACC);    \
    ACC = fdot2(BCH((HQ).w), BCH((WQ).w), ACC);

#define SDECL(i) uint4 s##i##_0, s##i##_1, s##i##_2, s##i##_3, s##i##_4, s##i##_5, s##i##_6, s##i##_7
#define SLOAD(i)                          \
    s##i##_0 = wqs0[(0 * 5 + (i)) * 64];  \
    s##i##_1 = wqs0[(1 * 5 + (i)) * 64];  \
    s##i##_2 = wqs0[(2 * 5 + (i)) * 64];  \
    s##i##_3 = wqs0[(3 * 5 + (i)) * 64];  \
    s##i##_4 = wqs0[(4 * 5 + (i)) * 64];  \
    s##i##_5 = wqs0[(5 * 5 + (i)) * 64];  \
    s##i##_6 = wqs0[(6 * 5 + (i)) * 64];  \
    s##i##_7 = wqs0[(7 * 5 + (i)) * 64];

// group q: 5 static col-dots + 3 streamed col-dots (dots first, then refill stream bufs)
#define GROUPQ(q, HQ, B0, B1, B2)            \
    DOTQ(HQ, s0_##q, acc0)                   \
    DOTQ(HQ, s1_##q, acc1)                   \
    DOTQ(HQ, s2_##q, acc2)                   \
    DOTQ(HQ, s3_##q, acc3)                   \
    DOTQ(HQ, s4_##q, acc4)                   \
    DOTQ(HQ, B0, acc5)                       \
    DOTQ(HQ, B1, acc6)                       \
    DOTQ(HQ, B2, acc7)

#define REFILL(B0, B1, B2, g)                \
    B0 = wqs1[((g) * 3 + 0) * 64];           \
    B1 = wqs1[((g) * 3 + 1) * 64];           \
    B2 = wqs1[((g) * 3 + 2) * 64];

__global__ __launch_bounds__(512)
void rnn_seq(const float* __restrict__ h0,    // [NB][NH]
             const u16* __restrict__ U,       // [NB*NT][NH] f16
             u16* __restrict__ H,             // [NB*NT][NH] f16 (out)
             const uint4* __restrict__ Wpk) { // packed W_hh f16, 32768 uint4
    const int b = blockIdx.x;
    const int tid = threadIdx.x;
    const int w = tid >> 6, l = tid & 63;

    __shared__ __align__(16) u32 h2u[NH / 2];        // h as f16 pairs, 1 KiB
    __shared__ __align__(16) float part2[8][NH + 4]; // padded partials, ~16.1 KiB

    const uint4* __restrict__ wqs0 = Wpk + (size_t)w * 2560 + l;          // static sec
    const uint4* __restrict__ wqs1 = Wpk + 20480 + (size_t)w * 1536 + l;  // stream sec

    // Static bank: 40 named quads (cols 8l+0..4, 8 quads each), coalesced b128 loads.
    SDECL(0); SDECL(1); SDECL(2); SDECL(3); SDECL(4);
    SLOAD(0) SLOAD(1) SLOAD(2) SLOAD(3) SLOAD(4)

    float hreg = h0[b * NH + tid];
    if (tid < NH / 2) {
        float2 hv = *reinterpret_cast<const float2*>(&h0[b * NH + 2 * tid]);
        half2_t hp; hp[0] = (_Float16)hv.x; hp[1] = (_Float16)hv.y;
        h2u[tid] = __builtin_bit_cast(u32, hp);
    }
    __syncthreads();

    const u16* __restrict__ Urow = U + (size_t)b * NT * NH + tid;
    u16* __restrict__ Hrow = H + (size_t)b * NT * NH + tid;
    const uint4* __restrict__ hqb = reinterpret_cast<const uint4*>(h2u) + (w << 3);

    // Stream double-buffer (named, rule #20): prime with groups 0 and 1.
    uint4 pa0, pa1, pa2, pb0, pb1, pb2;
    REFILL(pa0, pa1, pa2, 0)
    REFILL(pb0, pb1, pb2, 1)

    uint4 hqA, hqB;

    for (int t = 0; t < NT; ++t) {
        const u16 ubits = Urow[(size_t)t * NH];   // consumed after dots

        float acc0 = 0.f, acc1 = 0.f, acc2 = 0.f, acc3 = 0.f;
        float acc4 = 0.f, acc5 = 0.f, acc6 = 0.f, acc7 = 0.f;

        hqA = hqb[0];
        hqB = hqb[1]; GROUPQ(0, hqA, pa0, pa1, pa2) REFILL(pa0, pa1, pa2, 2)
        hqA = hqb[2]; GROUPQ(1, hqB, pb0, pb1, pb2) REFILL(pb0, pb1, pb2, 3)
        hqB = hqb[3]; GROUPQ(2, hqA, pa0, pa1, pa2) REFILL(pa0, pa1, pa2, 4)
        hqA = hqb[4]; GROUPQ(3, hqB, pb0, pb1, pb2) REFILL(pb0, pb1, pb2, 5)
        hqB = hqb[5]; GROUPQ(4, hqA, pa0, pa1, pa2) REFILL(pa0, pa1, pa2, 6)
        hqA = hqb[6]; GROUPQ(5, hqB, pb0, pb1, pb2) REFILL(pb0, pb1, pb2, 7)
        hqB = hqb[7]; GROUPQ(6, hqA, pa0, pa1, pa2) REFILL(pa0, pa1, pa2, 0)  // next step g0
                      GROUPQ(7, hqB, pb0, pb1, pb2) REFILL(pb0, pb1, pb2, 1)  // next step g1

        // Partials: cols 8l+0..7 contiguous -> two float4 writes (row padded +4).
        float4 w0; w0.x = acc0; w0.y = acc1; w0.z = acc2; w0.w = acc3;
        float4 w1; w1.x = acc4; w1.y = acc5; w1.z = acc6; w1.w = acc7;
        *reinterpret_cast<float4*>(&part2[w][8 * l]) = w0;
        *reinterpret_cast<float4*>(&part2[w][8 * l + 4]) = w1;
        __syncthreads();

        // h[tid] update: 8-way k-chunk reduction (conflict-free strided reads).
        const float pre = ((part2[0][tid] + part2[1][tid]) + (part2[2][tid] + part2[3][tid]))
                        + ((part2[4][tid] + part2[5][tid]) + (part2[6][tid] + part2[7][tid]))
                        + htof(ubits);
        const float e = __expf(2.f * pre);
        hreg = 0.9f * hreg + 0.1f * (1.f - 2.f / (e + 1.f));
        const u16 hb = ftoh(hreg);
        Hrow[(size_t)t * NH] = hb;
        reinterpret_cast<u16*>(h2u)[tid] = hb;
        __syncthreads();
    }
}

// ---------------- Phase 3: Y[m][n] = H[m][:] @ W_hy[:,n] + b_y[n]  (fp32 out) ----------------
__global__ __launch_bounds__(256) void y_gemm(
        const u16* __restrict__ H,      // [M][NH] f16
        const float* __restrict__ Why,  // [NH][NO]
        const float* __restrict__ by,   // [NO]
        float* __restrict__ Y) {        // [M][NO]
    const int m0 = blockIdx.x * 64;
    const int tid = threadIdx.x;
    const int tn = tid & 15, tm = tid >> 4;
    __shared__ float As[64][68];    // [k][m]
    __shared__ float Bs[64][132];   // [k][n]
    float acc[4][8] = {};
    for (int k0 = 0; k0 < NH; k0 += 64) {
        #pragma unroll
        for (int p = 0; p < 4; ++p) {
            const int idx = tid + p * 256;
            const int r = idx >> 4;
            const int c4 = idx & 15;
            ushort4 v = *reinterpret_cast<const ushort4*>(&H[(size_t)(m0 + r) * NH + k0 + c4 * 4]);
            As[c4 * 4 + 0][r] = htof(v.x); As[c4 * 4 + 1][r] = htof(v.y);
            As[c4 * 4 + 2][r] = htof(v.z); As[c4 * 4 + 3][r] = htof(v.w);
        }
        #pragma unroll
        for (int p = 0; p < 8; ++p) {
            const int idx = tid + p * 256;
            const int r = idx >> 5;
            const int c4 = idx & 31;
            float4 v = *reinterpret_cast<const float4*>(&Why[(size_t)(k0 + r) * NO + c4 * 4]);
            *reinterpret_cast<float4*>(&Bs[r][c4 * 4]) = v;
        }
        __syncthreads();
        #pragma unroll
        for (int kk = 0; kk < 64; ++kk) {
            float4 av = *reinterpret_cast<const float4*>(&As[kk][tm * 4]);
            float4 b0 = *reinterpret_cast<const float4*>(&Bs[kk][tn * 8]);
            float4 b1 = *reinterpret_cast<const float4*>(&Bs[kk][tn * 8 + 4]);
            const float am[4] = {av.x, av.y, av.z, av.w};
            const float bn[8] = {b0.x, b0.y, b0.z, b0.w, b1.x, b1.y, b1.z, b1.w};
            #pragma unroll
            for (int i = 0; i < 4; ++i)
                #pragma unroll
                for (int j = 0; j < 8; ++j)
                    acc[i][j] += am[i] * bn[j];
        }
        __syncthreads();
    }
    float bias[8];
    #pragma unroll
    for (int j = 0; j < 8; ++j) bias[j] = by[tn * 8 + j];
    #pragma unroll
    for (int i = 0; i < 4; ++i) {
        const int m = m0 + tm * 4 + i;
        float4 o0, o1;
        o0.x = acc[i][0] + bias[0]; o0.y = acc[i][1] + bias[1];
        o0.z = acc[i][2] + bias[2]; o0.w = acc[i][3] + bias[3];
        o1.x = acc[i][4] + bias[4]; o1.y = acc[i][5] + bias[5];
        o1.z = acc[i][6] + bias[6]; o1.w = acc[i][7] + bias[7];
        *reinterpret_cast<float4*>(&Y[(size_t)m * NO + tn * 8]) = o0;
        *reinterpret_cast<float4*>(&Y[(size_t)m * NO + tn * 8 + 4]) = o1;
    }
}

extern "C" void kernel_launch(void* const* d_in, const int* in_sizes, int n_in,
                              void* d_out, int out_size, void* d_ws, size_t ws_size,
                              hipStream_t stream) {
    const float* u   = (const float*)d_in[0];   // [64][2048][128]
    const float* h0  = (const float*)d_in[1];   // [64][512]
    const float* Wuh = (const float*)d_in[2];   // [128][512]
    const float* Whh = (const float*)d_in[3];   // [512][512]
    const float* Why = (const float*)d_in[4];   // [512][128]
    const float* bh  = (const float*)d_in[5];   // [512]
    const float* by  = (const float*)d_in[6];   // [128]
    float* y = (float*)d_out;                   // [64][2048][128] fp32

    u16* Uws = (u16*)d_ws;                       // 128 MiB
    u16* Hws = Uws + (size_t)NB * NT * NH;       // 128 MiB
    uint4* Wpk = (uint4*)d_out;                  // 512 KiB, dead until y_gemm
    (void)in_sizes; (void)n_in; (void)out_size; (void)ws_size;

    wpack<<<dim3(128), 256, 0, stream>>>(Whh, Wpk);
    u_gemm<<<dim3(NH / 64, (NB * NT) / 64), 256, 0, stream>>>(u, Wuh, bh, Uws);
    rnn_seq<<<dim3(NB), 512, 0, stream>>>(h0, Uws, Hws, Wpk);
    y_gemm<<<dim3((NB * NT) / 64), 256, 0, stream>>>(Hws, Why, by, y);
}

// Round 6
// 3610.464 us; speedup vs baseline: 1.8947x; 1.7520x over previous
//
#include <hip/hip_runtime.h>
#include <cmath>

// Leaky RNN:  h_t = 0.9 h_{t-1} + 0.1 tanh(h W_hh + u_t W_uh + b_h);  y_t = h_t W_hy + b_y
// B=64, T=2048, N_in=128, N_h=512, N_out=128.
//
// Phase 2 (critical path): one WG per batch row, 512 threads = 8 waves.  The compiler
// pins this kernel at 128 VGPR no matter what, so the design FITS 128: W_hh is held in
// LDS (2 of 8 cols/lane, 128 KiB, step-invariant) + streamed from L2 (6 of 8 cols,
// 384 KB/step/CU) through a 2-group-deep double buffer of 12 NAMED uint4 (48 VGPR).
// Wave w owns k-eighth [64w,64w+64); lane l owns cols 8l+0..7.  v_dot2_f32_f16 MACs,
// fp32 accum.  Partials in part2[8][8][72] (scalar stores, <=2-way banks = free).
// h broadcast via LDS f16 pairs; U prefetched one step ahead; 2 barriers/step.
//
// ws: U (f16 [B*T][512], 128 MiB) | H (f16 [B*T][512], 128 MiB).
// Wpk (512 KiB packed f16 W_hh) lives in d_out (dead until y_gemm runs last).

#define NB 64
#define NT 2048
#define NI 128
#define NH 512
#define NO 128

typedef unsigned short u16;
typedef unsigned int u32;
typedef _Float16 half2_t __attribute__((ext_vector_type(2)));

__device__ __forceinline__ float fdot2(half2_t a, half2_t b, float c) {
#if __has_builtin(__builtin_amdgcn_fdot2)
    return __builtin_amdgcn_fdot2(a, b, c, false);
#else
    return c + (float)a[0] * (float)b[0] + (float)a[1] * (float)b[1];
#endif
}
#define BCH(u) __builtin_bit_cast(half2_t, (u))

__device__ __forceinline__ u16 ftoh(float x) { return __builtin_bit_cast(u16, (_Float16)x); }
__device__ __forceinline__ float htof(u16 x) { return (float)__builtin_bit_cast(_Float16, x); }

__device__ __forceinline__ u32 ldpair(const float* __restrict__ W, int k, int c) {
    half2_t v;
    v[0] = (_Float16)W[(size_t)k * NH + c];
    v[1] = (_Float16)W[(size_t)(k + 1) * NH + c];
    return __builtin_bit_cast(u32, v);
}

// ---------------- Phase 0: pack W_hh to f16 in consumer order ----------------
// Section A (LDS-resident, idx<8192):  w=idx>>10, r=idx&1023, t2=r>>6, q=t2>>1, i=t2&1,
//   l=r&63, col=8l+i.
// Section B (streamed, idx>=8192): j=idx-8192, w=j/3072, r=j%3072, t2=r>>6, q=t2/6,
//   i=t2%6, l=r&63, col=8l+2+i.
// Quad = k-pairs {kb,kb+2,kb+4,kb+6}, kb=64w+8q.
__global__ __launch_bounds__(256) void wpack(const float* __restrict__ Whh,
                                             uint4* __restrict__ Wpk) {
    const int idx = blockIdx.x * 256 + threadIdx.x;   // 0..32767
    int w, q, i, l, col;
    if (idx < 8192) {
        w = idx >> 10;
        const int r = idx & 1023;
        const int t2 = r >> 6;
        q = t2 >> 1; i = t2 & 1; l = r & 63;
        col = 8 * l + i;
    } else {
        const int j = idx - 8192;
        w = j / 3072;
        const int r = j - 3072 * w;
        const int t2 = r >> 6;
        q = t2 / 6; i = t2 - 6 * q; l = r & 63;
        col = 8 * l + 2 + i;
    }
    const int kb = 64 * w + 8 * q;
    uint4 o;
    o.x = ldpair(Whh, kb + 0, col);
    o.y = ldpair(Whh, kb + 2, col);
    o.z = ldpair(Whh, kb + 4, col);
    o.w = ldpair(Whh, kb + 6, col);
    Wpk[idx] = o;
}

// ---------------- Phase 1: U[m][n] = u[m][:] @ W_uh[:,n] + b_h[n]  (f16 out) ----------------
__global__ __launch_bounds__(256) void u_gemm(
        const float* __restrict__ A,    // u  [M][NI]
        const float* __restrict__ Bw,   // W_uh [NI][NH]
        const float* __restrict__ bh,   // [NH]
        u16* __restrict__ C) {          // U [M][NH] f16
    const int n0 = blockIdx.x * 64;
    const int m0 = blockIdx.y * 64;
    const int tid = threadIdx.x;
    const int tn = tid & 15, tm = tid >> 4;
    __shared__ float As[64][68];   // [k][m]
    __shared__ float Bs[64][68];   // [k][n]
    float acc[4][4] = {};
    for (int k0 = 0; k0 < NI; k0 += 64) {
        const int r = tid >> 4, c4 = tid & 15;
        #pragma unroll
        for (int p = 0; p < 4; ++p) {
            const int row = r + p * 16;
            float4 v = *reinterpret_cast<const float4*>(&A[(size_t)(m0 + row) * NI + k0 + c4 * 4]);
            As[c4 * 4 + 0][row] = v.x; As[c4 * 4 + 1][row] = v.y;
            As[c4 * 4 + 2][row] = v.z; As[c4 * 4 + 3][row] = v.w;
        }
        #pragma unroll
        for (int p = 0; p < 4; ++p) {
            const int row = r + p * 16;
            float4 v = *reinterpret_cast<const float4*>(&Bw[(size_t)(k0 + row) * NH + n0 + c4 * 4]);
            *reinterpret_cast<float4*>(&Bs[row][c4 * 4]) = v;
        }
        __syncthreads();
        #pragma unroll
        for (int kk = 0; kk < 64; ++kk) {
            float4 av = *reinterpret_cast<const float4*>(&As[kk][tm * 4]);
            float4 bv = *reinterpret_cast<const float4*>(&Bs[kk][tn * 4]);
            const float am[4] = {av.x, av.y, av.z, av.w};
            const float bn[4] = {bv.x, bv.y, bv.z, bv.w};
            #pragma unroll
            for (int i = 0; i < 4; ++i)
                #pragma unroll
                for (int j = 0; j < 4; ++j)
                    acc[i][j] += am[i] * bn[j];
        }
        __syncthreads();
    }
    float bias[4];
    #pragma unroll
    for (int j = 0; j < 4; ++j) bias[j] = bh[n0 + tn * 4 + j];
    #pragma unroll
    for (int i = 0; i < 4; ++i) {
        const int m = m0 + tm * 4 + i;
        ushort4 out;
        out.x = ftoh(acc[i][0] + bias[0]);
        out.y = ftoh(acc[i][1] + bias[1]);
        out.z = ftoh(acc[i][2] + bias[2]);
        out.w = ftoh(acc[i][3] + bias[3]);
        *reinterpret_cast<ushort4*>(&C[(size_t)m * NH + n0 + tn * 4]) = out;
    }
}

// ---------------- Phase 2: sequential recurrence ----------------
#define DOTQ(HQ, WQ, ACC)                          \
    ACC = fdot2(BCH((HQ).x), BCH((WQ).x), ACC);    \
    ACC = fdot2(BCH((HQ).y), BCH((WQ).y), ACC);    \
    ACC = fdot2(BCH((HQ).z), BCH((WQ).z), ACC);    \
    ACC = fdot2(BCH((HQ).w), BCH((WQ).w), ACC);

#define GDOTS(HQ, D0, D1, P0, P1, P2, P3, P4, P5)  \
    DOTQ(HQ, D0, acc0) DOTQ(HQ, D1, acc1)          \
    DOTQ(HQ, P0, acc2) DOTQ(HQ, P1, acc3)          \
    DOTQ(HQ, P2, acc4) DOTQ(HQ, P3, acc5)          \
    DOTQ(HQ, P4, acc6) DOTQ(HQ, P5, acc7)

// Refill one 6-quad stream group; imm offsets <=3072B, second ptr covers slots 4,5.
#define REFILL(P0, P1, P2, P3, P4, P5)             \
    P0 = wcurA[0];   P1 = wcurA[64];               \
    P2 = wcurA[128]; P3 = wcurA[192];              \
    P4 = wcurB[0];   P5 = wcurB[64];               \
    wcurA += 384; wcurB += 384;

__global__ __launch_bounds__(512)
void rnn_seq(const float* __restrict__ h0,    // [NB][NH]
             const u16* __restrict__ U,       // [NB*NT][NH] f16
             u16* __restrict__ H,             // [NB*NT][NH] f16 (out)
             const uint4* __restrict__ Wpk) { // packed W_hh f16, 32768 uint4
    const int b = blockIdx.x;
    const int tid = threadIdx.x;
    const int w = tid >> 6, l = tid & 63;

    __shared__ __align__(16) uint4 Wlds[8192];       // LDS-resident W slice, 128 KiB
    __shared__ __align__(16) float part2[8][8][72];  // partials, 18 KiB, conflict-free
    __shared__ __align__(16) u32 h2u[NH / 2];        // h as f16 pairs, 1 KiB

    // One-time copy of section A into LDS (coalesced b128).
    #pragma unroll
    for (int j = 0; j < 16; ++j) Wlds[j * 512 + tid] = Wpk[j * 512 + tid];

    float hreg = h0[b * NH + tid];
    if (tid < NH / 2) {
        float2 hv = *reinterpret_cast<const float2*>(&h0[b * NH + 2 * tid]);
        half2_t hp; hp[0] = (_Float16)hv.x; hp[1] = (_Float16)hv.y;
        h2u[tid] = __builtin_bit_cast(u32, hp);
    }
    __syncthreads();

    const u16* __restrict__ Urow = U + (size_t)b * NT * NH + tid;
    u16* __restrict__ Hrow = H + (size_t)b * NT * NH + tid;
    const uint4* __restrict__ ws0 = Wpk + 8192 + (size_t)w * 3072 + l;  // stream base (g0)
    const uint4* __restrict__ wlw = Wlds + w * 1024 + l;                // LDS-W base
    const uint4* __restrict__ hqb = reinterpret_cast<const uint4*>(h2u) + (w << 3);

    // Stream double-buffer: 12 named quads, primed with groups g0 (pa) and g1 (pb).
    const uint4* wcurA = ws0;
    const uint4* wcurB = ws0 + 256;
    uint4 pa0, pa1, pa2, pa3, pa4, pa5, pb0, pb1, pb2, pb3, pb4, pb5;
    REFILL(pa0, pa1, pa2, pa3, pa4, pa5)   // g0; wcurA -> g1
    REFILL(pb0, pb1, pb2, pb3, pb4, pb5)   // g1; wcurA -> g2 (loop steady state)

    // LDS-W rolling pair, primed with group 0's quads.
    uint4 dA0 = wlw[0], dA1 = wlw[64];
    uint4 dB0, dB1;

    u16 ub_cur = Urow[0];

    #pragma unroll 1
    for (int t = 0; t < NT; ++t) {
        const u16 ub_nxt = Urow[(size_t)(t + 1) * NH];   // one step ahead (safe: H follows U)

        uint4 hqA = hqb[0], hqB = hqb[1];
        float acc0 = 0.f, acc1 = 0.f, acc2 = 0.f, acc3 = 0.f;
        float acc4 = 0.f, acc5 = 0.f, acc6 = 0.f, acc7 = 0.f;

        // G0
        dB0 = wlw[2 * 64]; dB1 = wlw[3 * 64];
        GDOTS(hqA, dA0, dA1, pa0, pa1, pa2, pa3, pa4, pa5)
        hqA = hqb[2];
        REFILL(pa0, pa1, pa2, pa3, pa4, pa5)   // g2
        // G1
        dA0 = wlw[4 * 64]; dA1 = wlw[5 * 64];
        GDOTS(hqB, dB0, dB1, pb0, pb1, pb2, pb3, pb4, pb5)
        hqB = hqb[3];
        REFILL(pb0, pb1, pb2, pb3, pb4, pb5)   // g3
        // G2
        dB0 = wlw[6 * 64]; dB1 = wlw[7 * 64];
        GDOTS(hqA, dA0, dA1, pa0, pa1, pa2, pa3, pa4, pa5)
        hqA = hqb[4];
        REFILL(pa0, pa1, pa2, pa3, pa4, pa5)   // g4
        // G3
        dA0 = wlw[8 * 64]; dA1 = wlw[9 * 64];
        GDOTS(hqB, dB0, dB1, pb0, pb1, pb2, pb3, pb4, pb5)
        hqB = hqb[5];
        REFILL(pb0, pb1, pb2, pb3, pb4, pb5)   // g5
        // G4
        dB0 = wlw[10 * 64]; dB1 = wlw[11 * 64];
        GDOTS(hqA, dA0, dA1, pa0, pa1, pa2, pa3, pa4, pa5)
        hqA = hqb[6];
        REFILL(pa0, pa1, pa2, pa3, pa4, pa5)   // g6
        // G5
        dA0 = wlw[12 * 64]; dA1 = wlw[13 * 64];
        GDOTS(hqB, dB0, dB1, pb0, pb1, pb2, pb3, pb4, pb5)
        hqB = hqb[7];
        REFILL(pb0, pb1, pb2, pb3, pb4, pb5)   // g7
        wcurA = ws0; wcurB = ws0 + 256;        // rewind for g0/g1
        // G6
        dB0 = wlw[14 * 64]; dB1 = wlw[15 * 64];
        GDOTS(hqA, dA0, dA1, pa0, pa1, pa2, pa3, pa4, pa5)
        REFILL(pa0, pa1, pa2, pa3, pa4, pa5)   // g0 (next step)
        // G7
        dA0 = wlw[0]; dA1 = wlw[64];           // next step's g0 quads
        GDOTS(hqB, dB0, dB1, pb0, pb1, pb2, pb3, pb4, pb5)
        REFILL(pb0, pb1, pb2, pb3, pb4, pb5)   // g1 (next step); wcurA -> g2

        // Partials: col 8l+i -> part2[w][i][l]; lanes consecutive => conflict-free.
        part2[w][0][l] = acc0; part2[w][1][l] = acc1;
        part2[w][2][l] = acc2; part2[w][3][l] = acc3;
        part2[w][4][l] = acc4; part2[w][5][l] = acc5;
        part2[w][6][l] = acc6; part2[w][7][l] = acc7;
        __syncthreads();

        // Update h[tid]: 8-way k-chunk reduction; 72%32=8 => 8i+l distinct => free.
        const int ii = tid & 7, lr = tid >> 3;
        const float pre = (((part2[0][ii][lr] + part2[1][ii][lr])
                          + (part2[2][ii][lr] + part2[3][ii][lr]))
                         + ((part2[4][ii][lr] + part2[5][ii][lr])
                          + (part2[6][ii][lr] + part2[7][ii][lr])))
                        + htof(ub_cur);
        const float e = __expf(2.f * pre);
        hreg = 0.9f * hreg + 0.1f * (1.f - 2.f / (e + 1.f));
        const u16 hb = ftoh(hreg);
        Hrow[(size_t)t * NH] = hb;
        reinterpret_cast<u16*>(h2u)[tid] = hb;
        ub_cur = ub_nxt;
        __syncthreads();
    }
}

// ---------------- Phase 3: Y[m][n] = H[m][:] @ W_hy[:,n] + b_y[n]  (fp32 out) ----------------
__global__ __launch_bounds__(256) void y_gemm(
        const u16* __restrict__ H,      // [M][NH] f16
        const float* __restrict__ Why,  // [NH][NO]
        const float* __restrict__ by,   // [NO]
        float* __restrict__ Y) {        // [M][NO]
    const int m0 = blockIdx.x * 64;
    const int tid = threadIdx.x;
    const int tn = tid & 15, tm = tid >> 4;
    __shared__ float As[64][68];    // [k][m]
    __shared__ float Bs[64][132];   // [k][n]
    float acc[4][8] = {};
    for (int k0 = 0; k0 < NH; k0 += 64) {
        #pragma unroll
        for (int p = 0; p < 4; ++p) {
            const int idx = tid + p * 256;
            const int r = idx >> 4;
            const int c4 = idx & 15;
            ushort4 v = *reinterpret_cast<const ushort4*>(&H[(size_t)(m0 + r) * NH + k0 + c4 * 4]);
            As[c4 * 4 + 0][r] = htof(v.x); As[c4 * 4 + 1][r] = htof(v.y);
            As[c4 * 4 + 2][r] = htof(v.z); As[c4 * 4 + 3][r] = htof(v.w);
        }
        #pragma unroll
        for (int p = 0; p < 8; ++p) {
            const int idx = tid + p * 256;
            const int r = idx >> 5;
            const int c4 = idx & 31;
            float4 v = *reinterpret_cast<const float4*>(&Why[(size_t)(k0 + r) * NO + c4 * 4]);
            *reinterpret_cast<float4*>(&Bs[r][c4 * 4]) = v;
        }
        __syncthreads();
        #pragma unroll
        for (int kk = 0; kk < 64; ++kk) {
            float4 av = *reinterpret_cast<const float4*>(&As[kk][tm * 4]);
            float4 b0 = *reinterpret_cast<const float4*>(&Bs[kk][tn * 8]);
            float4 b1 = *reinterpret_cast<const float4*>(&Bs[kk][tn * 8 + 4]);
            const float am[4] = {av.x, av.y, av.z, av.w};
            const float bn[8] = {b0.x, b0.y, b0.z, b0.w, b1.x, b1.y, b1.z, b1.w};
            #pragma unroll
            for (int i = 0; i < 4; ++i)
                #pragma unroll
                for (int j = 0; j < 8; ++j)
                    acc[i][j] += am[i] * bn[j];
        }
        __syncthreads();
    }
    float bias[8];
    #pragma unroll
    for (int j = 0; j < 8; ++j) bias[j] = by[tn * 8 + j];
    #pragma unroll
    for (int i = 0; i < 4; ++i) {
        const int m = m0 + tm * 4 + i;
        float4 o0, o1;
        o0.x = acc[i][0] + bias[0]; o0.y = acc[i][1] + bias[1];
        o0.z = acc[i][2] + bias[2]; o0.w = acc[i][3] + bias[3];
        o1.x = acc[i][4] + bias[4]; o1.y = acc[i][5] + bias[5];
        o1.z = acc[i][6] + bias[6]; o1.w = acc[i][7] + bias[7];
        *reinterpret_cast<float4*>(&Y[(size_t)m * NO + tn * 8]) = o0;
        *reinterpret_cast<float4*>(&Y[(size_t)m * NO + tn * 8 + 4]) = o1;
    }
}

extern "C" void kernel_launch(void* const* d_in, const int* in_sizes, int n_in,
                              void* d_out, int out_size, void* d_ws, size_t ws_size,
                              hipStream_t stream) {
    const float* u   = (const float*)d_in[0];   // [64][2048][128]
    const float* h0  = (const float*)d_in[1];   // [64][512]
    const float* Wuh = (const float*)d_in[2];   // [128][512]
    const float* Whh = (const float*)d_in[3];   // [512][512]
    const float* Why = (const float*)d_in[4];   // [512][128]
    const float* bh  = (const float*)d_in[5];   // [512]
    const float* by  = (const float*)d_in[6];   // [128]
    float* y = (float*)d_out;                   // [64][2048][128] fp32

    u16* Uws = (u16*)d_ws;                       // 128 MiB
    u16* Hws = Uws + (size_t)NB * NT * NH;       // 128 MiB
    uint4* Wpk = (uint4*)d_out;                  // 512 KiB, dead until y_gemm
    (void)in_sizes; (void)n_in; (void)out_size; (void)ws_size;

    wpack<<<dim3(128), 256, 0, stream>>>(Whh, Wpk);
    u_gemm<<<dim3(NH / 64, (NB * NT) / 64), 256, 0, stream>>>(u, Wuh, bh, Uws);
    rnn_seq<<<dim3(NB), 512, 0, stream>>>(h0, Uws, Hws, Wpk);
    y_gemm<<<dim3((NB * NT) / 64), 256, 0, stream>>>(Hws, Why, by, y);
}